// Round 4
// baseline (194.354 us; speedup 1.0000x reference)
//
#include <hip/hip_runtime.h>

typedef __bf16 v8bf  __attribute__((ext_vector_type(8)));
typedef float  f32x4  __attribute__((ext_vector_type(4)));
typedef float  f32x16 __attribute__((ext_vector_type(16)));
typedef unsigned int u32;
typedef u32 u32x4 __attribute__((ext_vector_type(4)));

#define NI   31
#define DD   32
#define NHID 128

// pack two f32 -> one u32 of 2 bf16 (lo, hi)
__device__ __forceinline__ u32 cvtpk(float lo, float hi) {
    u32 r;
    asm("v_cvt_pk_bf16_f32 %0, %1, %2" : "=v"(r) : "v"(lo), "v"(hi));
    return r;
}

// Repack one 32x32 C-tile (post-accumulation) into the two B-fragments
// (ks = 2mt, 2mt+1) for the next layer's MFMA, applying leaky-relu(0.2) and
// bf16 conversion on the way.
// Derivation: B elem j of frag p at dest lane (c,hi') comes from C reg
// r = 8p + 4hi' + (j&3), source half hi_src = j>>2, same column c.
// v_permlane32_swap_b32 vdst, vsrc swaps vdst[32:63] <-> vsrc[0:31]
// ("row 1 of VDST with row 0 of VSRC").  So swap(a0, b0) yields
//   a0 = {a0.lower, b0.lower} = frag word 0 (elems 0,1)
//   b0 = {a0.upper, b0.upper} = frag word 2 (elems 4,5)
__device__ __forceinline__ void repack_tile(const f32x16 c, v8bf* f0, v8bf* f1) {
    f32x16 v;
    #pragma unroll
    for (int r = 0; r < 16; ++r) { float x = c[r]; v[r] = fmaxf(x, 0.2f * x); }
    #pragma unroll
    for (int p = 0; p < 2; ++p) {
        u32 a0 = cvtpk(v[8*p + 0], v[8*p + 1]);   // regs 8p..8p+3
        u32 a1 = cvtpk(v[8*p + 2], v[8*p + 3]);
        u32 b0 = cvtpk(v[8*p + 4], v[8*p + 5]);   // regs 8p+4..8p+7
        u32 b1 = cvtpk(v[8*p + 6], v[8*p + 7]);
        asm("v_permlane32_swap_b32 %0, %1" : "+v"(a0), "+v"(b0));
        asm("v_permlane32_swap_b32 %0, %1" : "+v"(a1), "+v"(b1));
        u32x4 wd = {a0, a1, b0, b1};
        if (p == 0) *f0 = __builtin_bit_cast(v8bf, wd);
        else        *f1 = __builtin_bit_cast(v8bf, wd);
    }
}

// acc C-init with per-feature bias: reg r (=4q+j) <-> feature mt*32+8q+4hi+j
__device__ __forceinline__ f32x16 bias_init(const float* bp, int mt, int hi) {
    f32x16 a;
    #pragma unroll
    for (int q = 0; q < 4; ++q) {
        f32x4 b = *(const f32x4*)&bp[mt * 32 + q * 8 + 4 * hi];
        #pragma unroll
        for (int j = 0; j < 4; ++j) a[q * 4 + j] = b[j];
    }
    return a;
}

// ---------------- prep (weight transpose->bf16) + init (z col 0, log_det) ----------------
__global__ void maf_prep(const float* __restrict__ W1, const float* __restrict__ W2,
                         const float* __restrict__ W3,
                         __bf16* __restrict__ WT2, __bf16* __restrict__ WT3,
                         __bf16* __restrict__ WT1,
                         const float* __restrict__ x, const float* __restrict__ p0,
                         float* __restrict__ zout, float* __restrict__ ldout) {
    int b = blockIdx.x, t = threadIdx.x;
    if (b < 2 * NI) {                 // W2/W3: [kin][fo] -> [fo][kin]
        int i = b % NI;
        const float* src = (b < NI ? W2 : W3) + (size_t)i * NHID * NHID;
        __bf16* dst = (b < NI ? WT2 : WT3) + (size_t)i * NHID * NHID;
        for (int j = 0; j < 64; ++j) {
            int e = j * 256 + t;
            int fo = e >> 7, kin = e & 127;
            dst[e] = (__bf16)src[kin * NHID + fo];
        }
    } else if (b < 3 * NI) {          // W1: [d][fo] -> [fo][d]
        int i = b - 2 * NI;
        const float* src = W1 + (size_t)i * DD * NHID;
        __bf16* dst = WT1 + (size_t)i * NHID * DD;
        for (int j = 0; j < 16; ++j) {
            int e = j * 256 + t;
            int fo = e >> 5, d = e & 31;
            dst[e] = (__bf16)src[d * NHID + fo];
        }
    } else {                          // init
        int row = (b - 3 * NI) * 256 + t;
        float s = p0[0], tt = p0[1];
        ldout[row] = s;
        zout[(size_t)row * DD] = x[(size_t)row * DD] * expf(s) + tt;
    }
}

// ---------------- main: fully register-resident 4-layer MLP, no LDS h, no barriers ----------------
__global__ __launch_bounds__(256, 2) void maf_main(
    const float* __restrict__ x,
    const __bf16* __restrict__ WT1, const __bf16* __restrict__ WT2,
    const __bf16* __restrict__ WT3,
    const float* __restrict__ b1, const float* __restrict__ b2,
    const float* __restrict__ b3,
    const float* __restrict__ W4, const float* __restrict__ b4,
    float* __restrict__ zout, float* __restrict__ ldout) {

    __shared__ __bf16 w4t[2 * NHID];                 // W4^T [o][k]

    const int t  = threadIdx.x;
    const int i  = blockIdx.x >> 7;                  // net 0..30
    const int bt = blockIdx.x & 127;                 // batch tile (256 rows)
    const int l  = t & 63;
    const int w  = t >> 6;
    const int c  = l & 31;
    const int hi = l >> 5;
    const int row0 = bt * 256 + w * 64;              // this wave's 64 batches

    w4t[t] = (__bf16)W4[(size_t)i * 2 * NHID + (t & 127) * 2 + (t >> 7)];
    __syncthreads();                                  // only barrier in kernel

    f32x16 acc[4][2];                                 // [mt][nt]
    v8bf Bf[2][8];                                    // [nt][ks] h fragments

    // ================= layer 1: K=32, A=W1^T from global, B=x from global =================
    {
        const __bf16* wb = WT1 + (size_t)i * NHID * DD;
        v8bf A1[4][2];
        #pragma unroll
        for (int mt = 0; mt < 4; ++mt)
            #pragma unroll
            for (int ks = 0; ks < 2; ++ks)
                A1[mt][ks] = *(const v8bf*)&wb[(mt * 32 + c) * DD + ks * 16 + hi * 8];
        v8bf Bx[2][2];
        #pragma unroll
        for (int nt = 0; nt < 2; ++nt)
            #pragma unroll
            for (int ks = 0; ks < 2; ++ks) {
                const float* xp = x + (size_t)(row0 + nt * 32 + c) * DD + ks * 16 + hi * 8;
                f32x4 x0 = *(const f32x4*)xp;
                f32x4 x1 = *(const f32x4*)(xp + 4);
                u32x4 wd = {cvtpk(x0[0], x0[1]), cvtpk(x0[2], x0[3]),
                            cvtpk(x1[0], x1[1]), cvtpk(x1[2], x1[3])};
                Bx[nt][ks] = __builtin_bit_cast(v8bf, wd);
            }
        const float* bp = b1 + i * NHID;
        #pragma unroll
        for (int mt = 0; mt < 4; ++mt)
            #pragma unroll
            for (int nt = 0; nt < 2; ++nt) {
                f32x16 a = bias_init(bp, mt, hi);
                a = __builtin_amdgcn_mfma_f32_32x32x16_bf16(A1[mt][0], Bx[nt][0], a, 0, 0, 0);
                a = __builtin_amdgcn_mfma_f32_32x32x16_bf16(A1[mt][1], Bx[nt][1], a, 0, 0, 0);
                acc[mt][nt] = a;
            }
    }
    #pragma unroll
    for (int mt = 0; mt < 4; ++mt)
        #pragma unroll
        for (int nt = 0; nt < 2; ++nt)
            repack_tile(acc[mt][nt], &Bf[nt][2 * mt], &Bf[nt][2 * mt + 1]);

    // ================= hidden layers 2,3: K=128, A from global, B from regs =================
#define HIDDEN(WTP, BP)                                                                   \
    {                                                                                     \
        const __bf16* wb = (WTP) + (size_t)i * NHID * NHID;                               \
        const float* bp = (BP) + i * NHID;                                                \
        _Pragma("unroll")                                                                 \
        for (int mt = 0; mt < 4; ++mt)                                                    \
            _Pragma("unroll")                                                             \
            for (int nt = 0; nt < 2; ++nt)                                                \
                acc[mt][nt] = bias_init(bp, mt, hi);                                      \
        _Pragma("unroll")                                                                 \
        for (int ks = 0; ks < 8; ++ks) {                                                  \
            v8bf A[4];                                                                    \
            _Pragma("unroll")                                                             \
            for (int mt = 0; mt < 4; ++mt)                                                \
                A[mt] = *(const v8bf*)&wb[(mt * 32 + c) * NHID + ks * 16 + hi * 8];       \
            _Pragma("unroll")                                                             \
            for (int mt = 0; mt < 4; ++mt)                                                \
                _Pragma("unroll")                                                         \
                for (int nt = 0; nt < 2; ++nt)                                            \
                    acc[mt][nt] = __builtin_amdgcn_mfma_f32_32x32x16_bf16(                \
                        A[mt], Bf[nt][ks], acc[mt][nt], 0, 0, 0);                         \
        }                                                                                 \
        _Pragma("unroll")                                                                 \
        for (int mt = 0; mt < 4; ++mt)                                                    \
            _Pragma("unroll")                                                             \
            for (int nt = 0; nt < 2; ++nt)                                                \
                repack_tile(acc[mt][nt], &Bf[nt][2 * mt], &Bf[nt][2 * mt + 1]);           \
    }

    HIDDEN(WT2, b2)
    HIDDEN(WT3, b3)
#undef HIDDEN

    // ================= layer 4: 2x128 strip via MFMA (A rows >=2 zero) =================
    {
        f32x16 acc4[2];
        #pragma unroll
        for (int nt = 0; nt < 2; ++nt)
            acc4[nt] = (f32x16){0.f,0.f,0.f,0.f,0.f,0.f,0.f,0.f,
                                0.f,0.f,0.f,0.f,0.f,0.f,0.f,0.f};
        #pragma unroll
        for (int ks = 0; ks < 8; ++ks) {
            v8bf a4 = {};
            if (c < 2)
                a4 = *(const v8bf*)&w4t[c * NHID + ks * 16 + hi * 8];
            #pragma unroll
            for (int nt = 0; nt < 2; ++nt)
                acc4[nt] = __builtin_amdgcn_mfma_f32_32x32x16_bf16(a4, Bf[nt][ks], acc4[nt], 0, 0, 0);
        }
        if (hi == 0) {                                 // reg0 = row0 = s, reg1 = row1 = t
            float s0 = b4[2 * i], t0 = b4[2 * i + 1];
            #pragma unroll
            for (int nt = 0; nt < 2; ++nt) {
                int row = row0 + nt * 32 + c;
                float s  = acc4[nt][0] + s0;
                float tt = acc4[nt][1] + t0;
                float xv = x[(size_t)row * DD + i + 1];
                zout[(size_t)row * DD + i + 1] = xv * expf(s) + tt;
                atomicAdd(&ldout[row], s);
            }
        }
    }
}

extern "C" void kernel_launch(void* const* d_in, const int* in_sizes, int n_in,
                              void* d_out, int out_size, void* d_ws, size_t ws_size,
                              hipStream_t stream) {
    (void)in_sizes; (void)n_in; (void)out_size; (void)ws_size;
    const float* x  = (const float*)d_in[0];
    const float* p0 = (const float*)d_in[1];
    const float* W1 = (const float*)d_in[2];
    const float* b1 = (const float*)d_in[3];
    const float* W2 = (const float*)d_in[4];
    const float* b2 = (const float*)d_in[5];
    const float* W3 = (const float*)d_in[6];
    const float* b3 = (const float*)d_in[7];
    const float* W4 = (const float*)d_in[8];
    const float* b4 = (const float*)d_in[9];

    float* zout  = (float*)d_out;
    float* ldout = zout + (size_t)32768 * DD;

    __bf16* WT2 = (__bf16*)d_ws;                    // [31][128][128]
    __bf16* WT3 = WT2 + (size_t)NI * NHID * NHID;   // [31][128][128]
    __bf16* WT1 = WT3 + (size_t)NI * NHID * NHID;   // [31][128][32]

    maf_prep<<<3 * NI + 128, 256, 0, stream>>>(W1, W2, W3, WT2, WT3, WT1,
                                               x, p0, zout, ldout);
    maf_main<<<NI * 128, 256, 0, stream>>>(x, WT1, WT2, WT3,
                                           b1, b2, b3, W4, b4, zout, ldout);
}

// Round 5
// 109.706 us; speedup vs baseline: 1.7716x; 1.7716x over previous
//
#include <hip/hip_runtime.h>

typedef __bf16 v8bf  __attribute__((ext_vector_type(8)));
typedef float  f32x4  __attribute__((ext_vector_type(4)));
typedef float  f32x16 __attribute__((ext_vector_type(16)));
typedef unsigned int u32;
typedef u32 u32x4 __attribute__((ext_vector_type(4)));
typedef unsigned short u16;

#define NI   31
#define DD   32
#define NHID 128
#define NCHUNK 32            // batch chunks per net -> grid = 31*32 = 992 blocks
#define ITERS  4             // 4 iters x 256 batches = 1024 rows per chunk
#define NET_EL 36864         // frag-major elements per net (73728 B)
#define W2F_EL 4096          // element offset of W2 frags in blob/LDS
#define W3F_EL 20480
#define LDS_W4T 73728        // byte offsets in LDS
#define LDS_BB  74240
#define LDS_BYTES 75008

__device__ __forceinline__ u32 cvtpk(float lo, float hi) {
    u32 r;
    asm("v_cvt_pk_bf16_f32 %0, %1, %2" : "=v"(r) : "v"(lo), "v"(hi));
    return r;
}

// C-tile (f32x16) -> two next-layer B-fragments, with leaky-relu + bf16.
// Verified in round 4 (passed, absmax 0.0156).
__device__ __forceinline__ void repack_tile(const f32x16 c, v8bf* f0, v8bf* f1) {
    f32x16 v;
    #pragma unroll
    for (int r = 0; r < 16; ++r) { float x = c[r]; v[r] = fmaxf(x, 0.2f * x); }
    #pragma unroll
    for (int p = 0; p < 2; ++p) {
        u32 a0 = cvtpk(v[8*p + 0], v[8*p + 1]);
        u32 a1 = cvtpk(v[8*p + 2], v[8*p + 3]);
        u32 b0 = cvtpk(v[8*p + 4], v[8*p + 5]);
        u32 b1 = cvtpk(v[8*p + 6], v[8*p + 7]);
        asm("v_permlane32_swap_b32 %0, %1" : "+v"(a0), "+v"(b0));
        asm("v_permlane32_swap_b32 %0, %1" : "+v"(a1), "+v"(b1));
        u32x4 wd = {a0, a1, b0, b1};
        if (p == 0) *f0 = __builtin_bit_cast(v8bf, wd);
        else        *f1 = __builtin_bit_cast(v8bf, wd);
    }
}

// ---------------- prep: weights -> fragment-major bf16 blob; plus init ----------------
// blob per net i (36864 el): [W1 frags: (mt*2+ks)*64+l, 8 el] [W2 frags: (mt*8+ks)*64+l]
// [W3 frags]. frag element (lane l=(hi*32+c), j) = W[kin = ks*16+hi*8+j][fo = mt*32+c].
__global__ void maf_prep(const float* __restrict__ W1, const float* __restrict__ W2,
                         const float* __restrict__ W3, __bf16* __restrict__ blob,
                         const float* __restrict__ x, const float* __restrict__ p0,
                         float* __restrict__ zout, float* __restrict__ ldout) {
    int b = blockIdx.x, t = threadIdx.x;
    __shared__ float panel[16 * 128];
    if (b < 3 * NI) {
        int kind = b / NI, i = b % NI;
        const float* src; __bf16* dst; int NKS;
        if (kind == 0)      { src = W2 + (size_t)i * NHID * NHID; dst = blob + (size_t)i * NET_EL + W2F_EL; NKS = 8; }
        else if (kind == 1) { src = W3 + (size_t)i * NHID * NHID; dst = blob + (size_t)i * NET_EL + W3F_EL; NKS = 8; }
        else                { src = W1 + (size_t)i * DD * NHID;   dst = blob + (size_t)i * NET_EL;          NKS = 2; }
        const int fo = t & 127, hi2 = t >> 7;
        const int mt = fo >> 5, c = fo & 31;
        for (int ksb = 0; ksb < NKS; ++ksb) {
            #pragma unroll
            for (int r = 0; r < 8; ++r) {
                int e = r * 256 + t;
                panel[e] = src[(size_t)(ksb * 16 + (e >> 7)) * NHID + (e & 127)];
            }
            __syncthreads();
            __bf16 tmp[8];
            #pragma unroll
            for (int j = 0; j < 8; ++j) tmp[j] = (__bf16)panel[(hi2 * 8 + j) * 128 + fo];
            *(u32x4*)&dst[((size_t)(mt * NKS + ksb) * 64 + hi2 * 32 + c) * 8] = *(u32x4*)tmp;
            __syncthreads();
        }
    } else {                          // init: z col 0, log_det = p0.s
        int row = (b - 3 * NI) * 256 + t;
        float s = p0[0], tt = p0[1];
        ldout[row] = s;
        zout[(size_t)row * DD] = x[(size_t)row * DD] * expf(s) + tt;
    }
}

// ---------------- main: persistent LDS weights, register h, batch loop ----------------
__global__ __launch_bounds__(256, 2) void maf_main(
    const float* __restrict__ x, const __bf16* __restrict__ blob,
    const float* __restrict__ b1, const float* __restrict__ b2,
    const float* __restrict__ b3,
    const float* __restrict__ W4, const float* __restrict__ b4,
    float* __restrict__ zout, float* __restrict__ ldout) {

    extern __shared__ __align__(16) char smem[];
    __bf16* w4t = (__bf16*)(smem + LDS_W4T);     // [2][128]
    __bf16* bb  = (__bf16*)(smem + LDS_BB);      // [3][128] bf16 biases
    const __bf16* wlds = (const __bf16*)smem;

    const int t = threadIdx.x;
    const int i = blockIdx.x / NCHUNK;
    const int chunk = blockIdx.x % NCHUNK;
    const int l = t & 63, w = t >> 6, c = l & 31, hi = l >> 5;

    // ---- stage all weights for net i (73728 B, linear copy) ----
    {
        const u32x4* src = (const u32x4*)(blob + (size_t)i * NET_EL);
        u32x4* dst = (u32x4*)smem;
        #pragma unroll
        for (int k = 0; k < 18; ++k) dst[k * 256 + t] = src[k * 256 + t];
        w4t[t] = (__bf16)W4[(size_t)i * 2 * NHID + (t & 127) * 2 + (t >> 7)];
        if (t < NHID) {
            bb[t]       = (__bf16)b1[i * NHID + t];
            bb[128 + t] = (__bf16)b2[i * NHID + t];
            bb[256 + t] = (__bf16)b3[i * NHID + t];
        }
    }
    __syncthreads();                              // only barrier in the kernel

    const u32 ones0 = (hi == 0) ? 0x3F80u : 0u;   // bf16 1.0 at k=0 for hi==0 lanes
    const v8bf Bones = __builtin_bit_cast(v8bf, (u32x4){ones0, 0u, 0u, 0u});
    const float s0 = b4[2 * i], t0 = b4[2 * i + 1];
    const f32x16 zz = {};

    f32x16 acc[4][2];
    v8bf Bf[2][8];
    v8bf Bx[2][2];

    // x B-fragment loader (f32 -> bf16 in-reg), 64 batches starting at R0
#define LOADX(R0)                                                                     \
    { _Pragma("unroll")                                                               \
      for (int nt = 0; nt < 2; ++nt)                                                  \
          _Pragma("unroll")                                                           \
          for (int ks = 0; ks < 2; ++ks) {                                            \
              const float* xp = x + (size_t)((R0) + nt * 32 + c) * DD + ks * 16 + hi * 8; \
              f32x4 x0 = *(const f32x4*)xp;                                           \
              f32x4 x1 = *(const f32x4*)(xp + 4);                                     \
              u32x4 wd = {cvtpk(x0[0], x0[1]), cvtpk(x0[2], x0[3]),                   \
                          cvtpk(x1[0], x1[1]), cvtpk(x1[2], x1[3])};                  \
              Bx[nt][ks] = __builtin_bit_cast(v8bf, wd);                              \
          } }

    // bias A-fragment: bias value in the k=0 column (hi==0 lanes), zeros elsewhere
#define ABIAS(BOFF, MT)                                                               \
    __builtin_bit_cast(v8bf, (u32x4){                                                 \
        (hi == 0) ? (u32)__builtin_bit_cast(u16, bb[(BOFF) + (MT) * 32 + c]) : 0u,    \
        0u, 0u, 0u})

#define HIDDEN(BASE_EL, BOFF)                                                         \
    {                                                                                 \
        _Pragma("unroll")                                                             \
        for (int mt = 0; mt < 4; ++mt) {                                              \
            v8bf Ab = ABIAS(BOFF, mt);                                                \
            acc[mt][0] = __builtin_amdgcn_mfma_f32_32x32x16_bf16(Ab, Bones, zz, 0, 0, 0); \
            acc[mt][1] = __builtin_amdgcn_mfma_f32_32x32x16_bf16(Ab, Bones, zz, 0, 0, 0); \
        }                                                                             \
        _Pragma("unroll")                                                             \
        for (int ks = 0; ks < 8; ++ks) {                                              \
            v8bf A[4];                                                                \
            _Pragma("unroll")                                                         \
            for (int mt = 0; mt < 4; ++mt)                                            \
                A[mt] = *(const v8bf*)&wlds[(BASE_EL) + ((mt * 8 + ks) * 64 + l) * 8]; \
            _Pragma("unroll")                                                         \
            for (int mt = 0; mt < 4; ++mt)                                            \
                _Pragma("unroll")                                                     \
                for (int nt = 0; nt < 2; ++nt)                                        \
                    acc[mt][nt] = __builtin_amdgcn_mfma_f32_32x32x16_bf16(            \
                        A[mt], Bf[nt][ks], acc[mt][nt], 0, 0, 0);                     \
        }                                                                             \
        _Pragma("unroll")                                                             \
        for (int mt = 0; mt < 4; ++mt)                                                \
            _Pragma("unroll")                                                         \
            for (int nt = 0; nt < 2; ++nt)                                            \
                repack_tile(acc[mt][nt], &Bf[nt][2 * mt], &Bf[nt][2 * mt + 1]);       \
    }

    LOADX(chunk * 1024 + w * 64)                  // prefetch iter 0

    for (int it = 0; it < ITERS; ++it) {
        const int row0 = chunk * 1024 + it * 256 + w * 64;

        // ---- layer 1: acc = b1 (bias-MFMA) + W1f * x ----
        #pragma unroll
        for (int mt = 0; mt < 4; ++mt) {
            v8bf Ab = ABIAS(0, mt);
            v8bf A0 = *(const v8bf*)&wlds[((mt * 2 + 0) * 64 + l) * 8];
            v8bf A1 = *(const v8bf*)&wlds[((mt * 2 + 1) * 64 + l) * 8];
            #pragma unroll
            for (int nt = 0; nt < 2; ++nt) {
                f32x16 a = __builtin_amdgcn_mfma_f32_32x32x16_bf16(Ab, Bones, zz, 0, 0, 0);
                a = __builtin_amdgcn_mfma_f32_32x32x16_bf16(A0, Bx[nt][0], a, 0, 0, 0);
                a = __builtin_amdgcn_mfma_f32_32x32x16_bf16(A1, Bx[nt][1], a, 0, 0, 0);
                acc[mt][nt] = a;
            }
        }
        #pragma unroll
        for (int mt = 0; mt < 4; ++mt)
            #pragma unroll
            for (int nt = 0; nt < 2; ++nt)
                repack_tile(acc[mt][nt], &Bf[nt][2 * mt], &Bf[nt][2 * mt + 1]);

        HIDDEN(W2F_EL, 128)       // layer 2
        HIDDEN(W3F_EL, 256)       // layer 3

        if (it + 1 < ITERS) LOADX(chunk * 1024 + (it + 1) * 256 + w * 64)

        // ---- layer 4: 2x128 strip (A rows >= 2 are zero) ----
        {
            f32x16 acc4[2];
            acc4[0] = zz; acc4[1] = zz;
            #pragma unroll
            for (int ks = 0; ks < 8; ++ks) {
                v8bf a4 = {};
                if (c < 2) a4 = *(const v8bf*)&w4t[c * NHID + ks * 16 + hi * 8];
                acc4[0] = __builtin_amdgcn_mfma_f32_32x32x16_bf16(a4, Bf[0][ks], acc4[0], 0, 0, 0);
                acc4[1] = __builtin_amdgcn_mfma_f32_32x32x16_bf16(a4, Bf[1][ks], acc4[1], 0, 0, 0);
            }
            if (hi == 0) {
                #pragma unroll
                for (int nt = 0; nt < 2; ++nt) {
                    int row = row0 + nt * 32 + c;
                    float s  = acc4[nt][0] + s0;
                    float tt = acc4[nt][1] + t0;
                    float xv = x[(size_t)row * DD + i + 1];
                    zout[(size_t)row * DD + i + 1] = xv * expf(s) + tt;
                    atomicAdd(&ldout[row], s);
                }
            }
        }
    }
#undef LOADX
#undef ABIAS
#undef HIDDEN
}

extern "C" void kernel_launch(void* const* d_in, const int* in_sizes, int n_in,
                              void* d_out, int out_size, void* d_ws, size_t ws_size,
                              hipStream_t stream) {
    (void)in_sizes; (void)n_in; (void)out_size; (void)ws_size;
    const float* x  = (const float*)d_in[0];
    const float* p0 = (const float*)d_in[1];
    const float* W1 = (const float*)d_in[2];
    const float* b1 = (const float*)d_in[3];
    const float* W2 = (const float*)d_in[4];
    const float* b2 = (const float*)d_in[5];
    const float* W3 = (const float*)d_in[6];
    const float* b3 = (const float*)d_in[7];
    const float* W4 = (const float*)d_in[8];
    const float* b4 = (const float*)d_in[9];

    float* zout  = (float*)d_out;
    float* ldout = zout + (size_t)32768 * DD;

    __bf16* blob = (__bf16*)d_ws;                 // [31][36864] frag-major bf16

    hipFuncSetAttribute((const void*)maf_main,
                        hipFuncAttributeMaxDynamicSharedMemorySize, LDS_BYTES);

    maf_prep<<<3 * NI + 128, 256, 0, stream>>>(W1, W2, W3, blob, x, p0, zout, ldout);
    maf_main<<<NI * NCHUNK, 256, LDS_BYTES, stream>>>(x, blob, b1, b2, b3, W4, b4,
                                                      zout, ldout);
}

// Round 6
// 98.693 us; speedup vs baseline: 1.9693x; 1.1116x over previous
//
#include <hip/hip_runtime.h>

typedef __bf16 v8bf  __attribute__((ext_vector_type(8)));
typedef float  f32x4  __attribute__((ext_vector_type(4)));
typedef float  f32x16 __attribute__((ext_vector_type(16)));
typedef unsigned int u32;
typedef u32 u32x4 __attribute__((ext_vector_type(4)));
typedef unsigned short u16;

#define NI   31
#define DD   32
#define NHID 128
#define NROW 32768
#define NCHUNK 32            // batch chunks per net -> grid = 31*32 = 992 blocks
#define ITERS  4             // 4 iters x 256 batches = 1024 rows per chunk
#define NET_EL 36864         // frag-major elements per net (73728 B)
#define W2F_EL 4096          // element offset of W2 frags in blob/LDS
#define W3F_EL 20480
#define LDS_W4T 73728        // byte offsets in main-kernel LDS
#define LDS_BB  74240
#define LDS_BYTES 75008

__device__ __forceinline__ u32 cvtpk(float lo, float hi) {
    u32 r;
    asm("v_cvt_pk_bf16_f32 %0, %1, %2" : "=v"(r) : "v"(lo), "v"(hi));
    return r;
}

// C-tile (f32x16) -> two next-layer B-fragments, leaky-relu + bf16. (verified r4/r5)
__device__ __forceinline__ void repack_tile(const f32x16 c, v8bf* f0, v8bf* f1) {
    f32x16 v;
    #pragma unroll
    for (int r = 0; r < 16; ++r) { float x = c[r]; v[r] = fmaxf(x, 0.2f * x); }
    #pragma unroll
    for (int p = 0; p < 2; ++p) {
        u32 a0 = cvtpk(v[8*p + 0], v[8*p + 1]);
        u32 a1 = cvtpk(v[8*p + 2], v[8*p + 3]);
        u32 b0 = cvtpk(v[8*p + 4], v[8*p + 5]);
        u32 b1 = cvtpk(v[8*p + 6], v[8*p + 7]);
        asm("v_permlane32_swap_b32 %0, %1" : "+v"(a0), "+v"(b0));
        asm("v_permlane32_swap_b32 %0, %1" : "+v"(a1), "+v"(b1));
        u32x4 wd = {a0, a1, b0, b1};
        if (p == 0) *f0 = __builtin_bit_cast(v8bf, wd);
        else        *f1 = __builtin_bit_cast(v8bf, wd);
    }
}

// ---------------- prep ----------------
// blocks 0..92: weights -> fragment-major bf16 blob (verified r5)
// blocks 93..220: x -> (a) xfrag: frag-major bf16, (b) xT: [32][32768] f32,
//                 (c) z col 0 + ldout init
__global__ void maf_prep(const float* __restrict__ W1, const float* __restrict__ W2,
                         const float* __restrict__ W3, __bf16* __restrict__ blob,
                         __bf16* __restrict__ xfrag, float* __restrict__ xT,
                         const float* __restrict__ x, const float* __restrict__ p0,
                         float* __restrict__ zout, float* __restrict__ ldout) {
    int b = blockIdx.x, t = threadIdx.x;
    if (b < 3 * NI) {
        __shared__ float panel[16 * 128];
        int kind = b / NI, i = b % NI;
        const float* src; __bf16* dst; int NKS;
        if (kind == 0)      { src = W2 + (size_t)i * NHID * NHID; dst = blob + (size_t)i * NET_EL + W2F_EL; NKS = 8; }
        else if (kind == 1) { src = W3 + (size_t)i * NHID * NHID; dst = blob + (size_t)i * NET_EL + W3F_EL; NKS = 8; }
        else                { src = W1 + (size_t)i * DD * NHID;   dst = blob + (size_t)i * NET_EL;          NKS = 2; }
        const int fo = t & 127, hi2 = t >> 7;
        const int mt = fo >> 5, c = fo & 31;
        for (int ksb = 0; ksb < NKS; ++ksb) {
            #pragma unroll
            for (int r = 0; r < 8; ++r) {
                int e = r * 256 + t;
                panel[e] = src[(size_t)(ksb * 16 + (e >> 7)) * NHID + (e & 127)];
            }
            __syncthreads();
            __bf16 tmp[8];
            #pragma unroll
            for (int j = 0; j < 8; ++j) tmp[j] = (__bf16)panel[(hi2 * 8 + j) * 128 + fo];
            *(u32x4*)&dst[((size_t)(mt * NKS + ksb) * 64 + hi2 * 32 + c) * 8] = *(u32x4*)tmp;
            __syncthreads();
        }
    } else {
        __shared__ float pan[64 * 33];                    // padded: conflict-free col reads
        const int xb = b - 3 * NI;                        // 0..127, owns 256 rows
        const float s0 = p0[0], t0 = p0[1];
        const float es = expf(s0);
        for (int pass = 0; pass < 4; ++pass) {
            const int rb = xb * 256 + pass * 64;          // 64-row group base
            #pragma unroll
            for (int r = 0; r < 8; ++r) {
                int e = r * 256 + t;                      // 2048 f32
                pan[(e >> 5) * 33 + (e & 31)] = x[(size_t)(rb + (e >> 5)) * DD + (e & 31)];
            }
            __syncthreads();
            // xT: dim-major f32
            {
                int row = t & 63, dbase = (t >> 6) * 8;
                #pragma unroll
                for (int dd = 0; dd < 8; ++dd)
                    xT[(size_t)(dbase + dd) * NROW + rb + row] = pan[row * 33 + dbase + dd];
            }
            // xfrag: 4 fragments (nt,ks) for this 64-row group, one per wave
            {
                int w2 = t >> 6, l = t & 63;
                int nt = w2 >> 1, ks = w2 & 1;
                int c = l & 31, hi = l >> 5;
                const float* pr = &pan[(nt * 32 + c) * 33 + ks * 16 + hi * 8];
                f32x4 x0 = *(const f32x4*)pr;
                f32x4 x1 = *(const f32x4*)(pr + 4);
                u32x4 wd = {cvtpk(x0[0], x0[1]), cvtpk(x0[2], x0[3]),
                            cvtpk(x1[0], x1[1]), cvtpk(x1[2], x1[3])};
                *(u32x4*)&xfrag[(size_t)(rb >> 6) * 2048 + ((w2 * 64 + l) << 3)] = wd;
            }
            // init z col 0 + ldout
            if (t < 64) {
                int row = rb + t;
                ldout[row] = s0;
                zout[(size_t)row * DD] = pan[t * 33] * es + t0;
            }
            __syncthreads();
        }
    }
}

// ---------------- main: persistent LDS weights, register h, batch loop ----------------
__global__ __launch_bounds__(256, 2) void maf_main(
    const __bf16* __restrict__ xfrag, const float* __restrict__ xT,
    const __bf16* __restrict__ blob,
    const float* __restrict__ b1, const float* __restrict__ b2,
    const float* __restrict__ b3,
    const float* __restrict__ W4, const float* __restrict__ b4,
    float* __restrict__ zout, float* __restrict__ ldout) {

    extern __shared__ __align__(16) char smem[];
    __bf16* w4t = (__bf16*)(smem + LDS_W4T);     // [2][128]
    __bf16* bb  = (__bf16*)(smem + LDS_BB);      // [3][128] bf16 biases
    const __bf16* wlds = (const __bf16*)smem;

    const int t = threadIdx.x;
    const int i = blockIdx.x / NCHUNK;
    const int chunk = blockIdx.x % NCHUNK;
    const int l = t & 63, w = t >> 6, c = l & 31, hi = l >> 5;
    const bool full_k1 = (i >= 16);               // dims 16..31 nonzero only for i>=16

    // ---- stage all weights for net i (73728 B, linear copy) ----
    {
        const u32x4* src = (const u32x4*)(blob + (size_t)i * NET_EL);
        u32x4* dst = (u32x4*)smem;
        #pragma unroll
        for (int k = 0; k < 18; ++k) dst[k * 256 + t] = src[k * 256 + t];
        w4t[t] = (__bf16)W4[(size_t)i * 2 * NHID + (t & 127) * 2 + (t >> 7)];
        if (t < NHID) {
            bb[t]       = (__bf16)b1[i * NHID + t];
            bb[128 + t] = (__bf16)b2[i * NHID + t];
            bb[256 + t] = (__bf16)b3[i * NHID + t];
        }
    }
    __syncthreads();                              // only barrier in the kernel

    const u32 ones0 = (hi == 0) ? 0x3F80u : 0u;   // bf16 1.0 at k=0 for hi==0 lanes
    const v8bf Bones = __builtin_bit_cast(v8bf, (u32x4){ones0, 0u, 0u, 0u});
    const float s0 = b4[2 * i], t0 = b4[2 * i + 1];
    const f32x16 zz = {};

    f32x16 acc[4][2];
    v8bf Bf[2][8];
    v8bf Bx[2][2];

    // x B-fragments: 4 coalesced 1KB loads from frag-major xfrag (group G = row0/64)
#define LOADX(G)                                                                      \
    { const __bf16* xg = xfrag + (size_t)(G) * 2048;                                  \
      Bx[0][0] = *(const v8bf*)&xg[(0 * 64 + l) << 3];                                \
      if (full_k1) Bx[0][1] = *(const v8bf*)&xg[(1 * 64 + l) << 3];                   \
      Bx[1][0] = *(const v8bf*)&xg[(2 * 64 + l) << 3];                                \
      if (full_k1) Bx[1][1] = *(const v8bf*)&xg[(3 * 64 + l) << 3]; }

    // bias A-fragment: bias value in the k=0 column (hi==0 lanes), zeros elsewhere
#define ABIAS(BOFF, MT)                                                               \
    __builtin_bit_cast(v8bf, (u32x4){                                                 \
        (hi == 0) ? (u32)__builtin_bit_cast(u16, bb[(BOFF) + (MT) * 32 + c]) : 0u,    \
        0u, 0u, 0u})

#define HIDDEN(BASE_EL, BOFF)                                                         \
    {                                                                                 \
        _Pragma("unroll")                                                             \
        for (int mt = 0; mt < 4; ++mt) {                                              \
            v8bf Ab = ABIAS(BOFF, mt);                                                \
            acc[mt][0] = __builtin_amdgcn_mfma_f32_32x32x16_bf16(Ab, Bones, zz, 0, 0, 0); \
            acc[mt][1] = __builtin_amdgcn_mfma_f32_32x32x16_bf16(Ab, Bones, zz, 0, 0, 0); \
        }                                                                             \
        _Pragma("unroll")                                                             \
        for (int ks = 0; ks < 8; ++ks) {                                              \
            v8bf A[4];                                                                \
            _Pragma("unroll")                                                         \
            for (int mt = 0; mt < 4; ++mt)                                            \
                A[mt] = *(const v8bf*)&wlds[(BASE_EL) + ((mt * 8 + ks) * 64 + l) * 8]; \
            _Pragma("unroll")                                                         \
            for (int mt = 0; mt < 4; ++mt)                                            \
                _Pragma("unroll")                                                     \
                for (int nt = 0; nt < 2; ++nt)                                        \
                    acc[mt][nt] = __builtin_amdgcn_mfma_f32_32x32x16_bf16(            \
                        A[mt], Bf[nt][ks], acc[mt][nt], 0, 0, 0);                     \
        }                                                                             \
        _Pragma("unroll")                                                             \
        for (int mt = 0; mt < 4; ++mt)                                                \
            _Pragma("unroll")                                                         \
            for (int nt = 0; nt < 2; ++nt)                                            \
                repack_tile(acc[mt][nt], &Bf[nt][2 * mt], &Bf[nt][2 * mt + 1]);       \
    }

    LOADX((chunk * 1024 + w * 64) >> 6)           // prefetch iter 0

    for (int it = 0; it < ITERS; ++it) {
        const int row0 = chunk * 1024 + it * 256 + w * 64;

        // ---- layer 1: acc = b1 (bias-MFMA) + W1f * x ----
        #pragma unroll
        for (int mt = 0; mt < 4; ++mt) {
            v8bf Ab = ABIAS(0, mt);
            v8bf A0 = *(const v8bf*)&wlds[((mt * 2 + 0) * 64 + l) * 8];
            v8bf A1;
            if (full_k1) A1 = *(const v8bf*)&wlds[((mt * 2 + 1) * 64 + l) * 8];
            #pragma unroll
            for (int nt = 0; nt < 2; ++nt) {
                f32x16 a = __builtin_amdgcn_mfma_f32_32x32x16_bf16(Ab, Bones, zz, 0, 0, 0);
                a = __builtin_amdgcn_mfma_f32_32x32x16_bf16(A0, Bx[nt][0], a, 0, 0, 0);
                if (full_k1)
                    a = __builtin_amdgcn_mfma_f32_32x32x16_bf16(A1, Bx[nt][1], a, 0, 0, 0);
                acc[mt][nt] = a;
            }
        }
        #pragma unroll
        for (int mt = 0; mt < 4; ++mt)
            #pragma unroll
            for (int nt = 0; nt < 2; ++nt)
                repack_tile(acc[mt][nt], &Bf[nt][2 * mt], &Bf[nt][2 * mt + 1]);

        if (it + 1 < ITERS)                       // early prefetch: Bx dead after layer 1
            LOADX((chunk * 1024 + (it + 1) * 256 + w * 64) >> 6)

        HIDDEN(W2F_EL, 128)       // layer 2
        HIDDEN(W3F_EL, 256)       // layer 3

        // ---- layer 4: 2x128 strip (A rows >= 2 are zero) ----
        {
            f32x16 acc4[2];
            acc4[0] = zz; acc4[1] = zz;
            #pragma unroll
            for (int ks = 0; ks < 8; ++ks) {
                v8bf a4 = {};
                if (c < 2) a4 = *(const v8bf*)&w4t[c * NHID + ks * 16 + hi * 8];
                acc4[0] = __builtin_amdgcn_mfma_f32_32x32x16_bf16(a4, Bf[0][ks], acc4[0], 0, 0, 0);
                acc4[1] = __builtin_amdgcn_mfma_f32_32x32x16_bf16(a4, Bf[1][ks], acc4[1], 0, 0, 0);
            }
            if (hi == 0) {
                #pragma unroll
                for (int nt = 0; nt < 2; ++nt) {
                    int row = row0 + nt * 32 + c;
                    float s  = acc4[nt][0] + s0;
                    float tt = acc4[nt][1] + t0;
                    float xv = xT[(size_t)(i + 1) * NROW + row];   // coalesced
                    zout[(size_t)row * DD + i + 1] = xv * expf(s) + tt;
                    atomicAdd(&ldout[row], s);
                }
            }
        }
    }
#undef LOADX
#undef ABIAS
#undef HIDDEN
}

extern "C" void kernel_launch(void* const* d_in, const int* in_sizes, int n_in,
                              void* d_out, int out_size, void* d_ws, size_t ws_size,
                              hipStream_t stream) {
    (void)in_sizes; (void)n_in; (void)out_size; (void)ws_size;
    const float* x  = (const float*)d_in[0];
    const float* p0 = (const float*)d_in[1];
    const float* W1 = (const float*)d_in[2];
    const float* b1 = (const float*)d_in[3];
    const float* W2 = (const float*)d_in[4];
    const float* b2 = (const float*)d_in[5];
    const float* W3 = (const float*)d_in[6];
    const float* b3 = (const float*)d_in[7];
    const float* W4 = (const float*)d_in[8];
    const float* b4 = (const float*)d_in[9];

    float* zout  = (float*)d_out;
    float* ldout = zout + (size_t)NROW * DD;

    __bf16* blob  = (__bf16*)d_ws;                          // 31*36864 bf16 = 2.29 MB
    __bf16* xfrag = blob + (size_t)NI * NET_EL;             // 32768*32 bf16 = 2 MB
    float*  xT    = (float*)(xfrag + (size_t)NROW * DD);    // 32*32768 f32 = 4 MB

    hipFuncSetAttribute((const void*)maf_main,
                        hipFuncAttributeMaxDynamicSharedMemorySize, LDS_BYTES);

    maf_prep<<<3 * NI + 128, 256, 0, stream>>>(W1, W2, W3, blob, xfrag, xT,
                                               x, p0, zout, ldout);
    maf_main<<<NI * NCHUNK, 256, LDS_BYTES, stream>>>(xfrag, xT, blob,
                                                      b1, b2, b3, W4, b4, zout, ldout);
}